// Round 13
// baseline (358.436 us; speedup 1.0000x reference)
//
#include <hip/hip_runtime.h>
#include <cmath>

#define T_TOK 4096
#define DM    512
#define DFF   2048
#define NE    16
#define PP    128
#define WROW  520   // padded LDS row stride in shorts (1040 B): 2-way conflicts = free

typedef __attribute__((ext_vector_type(8))) short bfrag;      // 8 bf16 (4 VGPRs)
typedef __attribute__((ext_vector_type(4))) float f32x4;
typedef __attribute__((ext_vector_type(8))) unsigned short us8;

__device__ __forceinline__ unsigned short f2bf(float f) {
  unsigned int u = __float_as_uint(f);
  unsigned int r = (u + 0x7FFFu + ((u >> 16) & 1u)) >> 16;
  return (unsigned short)r;
}
__device__ __forceinline__ float bf2f(unsigned short b) {
  return __uint_as_float(((unsigned int)b) << 16);
}

#define GLOAD_LDS16(g, l) __builtin_amdgcn_global_load_lds( \
    (const __attribute__((address_space(1))) void*)(g), \
    (__attribute__((address_space(3))) void*)(l), 16, 0, 0)

// ---------------------------------------------------------------------------
// Wx = W_ih @ Wp  ->  Bigcat x-part rows [0,384)
// ---------------------------------------------------------------------------
__global__ __launch_bounds__(256) void wx_gemm(
    const float* __restrict__ W_ih, const float* __restrict__ Wp,
    float* __restrict__ Bigcat)
{
  __shared__ float Bs[128][65];
  int kb = blockIdx.x * 64, nb = blockIdx.y * 64;
  int tid = threadIdx.x;
  #pragma unroll
  for (int i = 0; i < 8; ++i) {
    int s = tid + i * 256;              // 0..2047 float4 slots
    int r = s >> 4, c4 = (s & 15) * 4;
    float4 v = *(const float4*)(Wp + (size_t)r * 512 + kb + c4);
    Bs[r][c4] = v.x; Bs[r][c4+1] = v.y; Bs[r][c4+2] = v.z; Bs[r][c4+3] = v.w;
  }
  __syncthreads();
  int tx = tid & 15, ty = tid >> 4;
  float acc[4][4] = {{0.f}};
  const float* a0 = W_ih + (size_t)(nb + ty * 4) * 128;
  #pragma unroll 4
  for (int p = 0; p < 128; ++p) {
    float a[4], b[4];
    #pragma unroll
    for (int i = 0; i < 4; ++i) a[i] = a0[(size_t)i * 128 + p];
    #pragma unroll
    for (int j = 0; j < 4; ++j) b[j] = Bs[p][tx * 4 + j];
    #pragma unroll
    for (int i = 0; i < 4; ++i)
      #pragma unroll
      for (int j = 0; j < 4; ++j)
        acc[i][j] += a[i] * b[j];
  }
  #pragma unroll
  for (int i = 0; i < 4; ++i)
    #pragma unroll
    for (int j = 0; j < 4; ++j)
      Bigcat[(size_t)(nb + ty * 4 + i) * 640 + kb + tx * 4 + j] = acc[i][j];
}

// ---------------------------------------------------------------------------
// fill Bigcat h-part + zero rows, bcat (incl. W_ih@bp term), cnt
// ---------------------------------------------------------------------------
__global__ void fill_big(const float* __restrict__ W_ih, const float* __restrict__ W_hh,
                         const float* __restrict__ bp,
                         const float* __restrict__ b_ih, const float* __restrict__ b_hh,
                         float* __restrict__ Bigcat, float* __restrict__ bcat,
                         int* __restrict__ cnt)
{
  int id = blockIdx.x * 256 + threadIdx.x;   // 131072
  if (blockIdx.x == 0 && threadIdx.x < NE) cnt[threadIdx.x] = 0;
  if (id < 512) {
    float bvec = 0.f;
    if (id < 384) {
      const float* wr = W_ih + (size_t)id * 128;
      #pragma unroll 8
      for (int p = 0; p < 128; ++p) bvec += wr[p] * bp[p];
    }
    float b = (id < 256) ? (b_ih[id] + bvec + b_hh[id])
            : (id < 384) ? (b_ih[id] + bvec) : b_hh[id - 128];
    bcat[id] = b;
  }
  if (id < 65536) {                          // h-part cols [512,640)
    int n = id >> 7, jj = id & 127;
    float v = (n < 256) ? W_hh[n * 128 + jj]
            : (n < 384) ? 0.f : W_hh[(n - 128) * 128 + jj];
    Bigcat[(size_t)n * 640 + 512 + jj] = v;
  } else {                                   // zero x-part rows [384,512)
    int u = id - 65536;
    int n = 384 + (u >> 9), k = u & 511;
    Bigcat[(size_t)n * 640 + k] = 0.f;
  }
}

// ---------------------------------------------------------------------------
// Fused gate GEMM: gs[T,512] = [x | h_prev] @ Bigcat^T + bcat   (K = 640)
// ---------------------------------------------------------------------------
__global__ __launch_bounds__(256) void sgemm_big(
    const float* __restrict__ A1, const float* __restrict__ A2,
    const float* __restrict__ B, const float* __restrict__ bias,
    float* __restrict__ C)
{
  __shared__ __align__(16) float As[16][68];
  __shared__ __align__(16) float Bs[16][68];
  const int bm = blockIdx.x * 64;
  const int bn = blockIdx.y * 64;
  const int tid = threadIdx.x;
  const int tx = tid & 15;
  const int ty = tid >> 4;

  float acc[4][4] = {{0.f}};

  for (int k0 = 0; k0 < 640; k0 += 16) {
    {
      int r  = tid >> 2;
      int c4 = (tid & 3) * 4;
      const float* src = (k0 < 512) ? (A1 + (size_t)(bm + r) * 512 + k0 + c4)
                                    : (A2 + (size_t)(bm + r) * 128 + (k0 - 512) + c4);
      float4 v = *(const float4*)src;
      As[c4+0][r] = v.x; As[c4+1][r] = v.y; As[c4+2][r] = v.z; As[c4+3][r] = v.w;
    }
    {
      int r  = tid >> 2;
      int c4 = (tid & 3) * 4;
      float4 v = *(const float4*)(B + (size_t)(bn + r) * 640 + k0 + c4);
      Bs[c4+0][r] = v.x; Bs[c4+1][r] = v.y; Bs[c4+2][r] = v.z; Bs[c4+3][r] = v.w;
    }
    __syncthreads();
    #pragma unroll
    for (int k = 0; k < 16; ++k) {
      float4 a4 = *(const float4*)&As[k][ty*4];
      float4 b4 = *(const float4*)&Bs[k][tx*4];
      float a[4] = {a4.x, a4.y, a4.z, a4.w};
      float b[4] = {b4.x, b4.y, b4.z, b4.w};
      #pragma unroll
      for (int i = 0; i < 4; ++i)
        #pragma unroll
        for (int j = 0; j < 4; ++j)
          acc[i][j] += a[i] * b[j];
    }
    __syncthreads();
  }
  #pragma unroll
  for (int i = 0; i < 4; ++i) {
    int row = bm + ty*4 + i;
    #pragma unroll
    for (int j = 0; j < 4; ++j) {
      int col = bn + tx*4 + j;
      C[(size_t)row * 512 + col] = acc[i][j] + bias[col];
    }
  }
}

// ---------------------------------------------------------------------------
// GRU elementwise from fused gate buffer s[T,512]
// ---------------------------------------------------------------------------
__global__ void gru_elem2(const float* __restrict__ s, const float* __restrict__ hprev,
                          float* __restrict__ hout)
{
  int i = blockIdx.x * blockDim.x + threadIdx.x;
  int t = i >> 7, p = i & 127;
  const float* sr = s + (size_t)t * 512;
  float rz = sr[p], zz = sr[128 + p], xn = sr[256 + p], hn = sr[384 + p];
  float r = 1.f / (1.f + expf(-rz));
  float z = 1.f / (1.f + expf(-zz));
  float n = tanhf(xn + r * hn);
  hout[i] = (1.f - z) * n + z * hprev[i];
}

// ---------------------------------------------------------------------------
// Router v2: one token per thread, Wr in LDS, per-block histogram ranking.
// ---------------------------------------------------------------------------
__global__ __launch_bounds__(64) void router_topk2(
    const float* __restrict__ h, const float* __restrict__ Wr,
    const float* __restrict__ br,
    float* __restrict__ wgt, int* __restrict__ tokslot,
    int* __restrict__ cnt)
{
  __shared__ float4 wr4[NE * 32];     // 8 KB
  __shared__ float br_s[NE];
  __shared__ int hist[NE];
  __shared__ int basex[NE];

  int tid = threadIdx.x;
  #pragma unroll
  for (int i = 0; i < 8; ++i)
    wr4[tid + i * 64] = ((const float4*)Wr)[tid + i * 64];
  if (tid < NE) { br_s[tid] = br[tid]; hist[tid] = 0; }
  __syncthreads();

  int t = blockIdx.x * 64 + tid;
  const float4* hr = (const float4*)(h + (size_t)t * PP);

  float logit[NE];
  #pragma unroll
  for (int e = 0; e < NE; ++e) logit[e] = 0.f;
  #pragma unroll 4
  for (int i = 0; i < 32; ++i) {
    float4 v = hr[i];
    #pragma unroll
    for (int e = 0; e < NE; ++e) {
      float4 w = wr4[e * 32 + i];
      logit[e] += v.x * w.x + v.y * w.y + v.z * w.z + v.w * w.w;
    }
  }
  #pragma unroll
  for (int e = 0; e < NE; ++e) logit[e] += br_s[e];

  float mx = logit[0];
  #pragma unroll
  for (int e = 1; e < NE; ++e) mx = fmaxf(mx, logit[e]);
  float p[NE];
  #pragma unroll
  for (int e = 0; e < NE; ++e) p[e] = expf(logit[e] - mx);
  int i0 = 0; float m0 = p[0];
  #pragma unroll
  for (int e = 1; e < NE; ++e) { if (p[e] > m0) { m0 = p[e]; i0 = e; } }
  int i1 = -1; float m1 = -1.f;
  #pragma unroll
  for (int e = 0; e < NE; ++e) { if (e != i0 && p[e] > m1) { m1 = p[e]; i1 = e; } }
  float inv = 1.f / (m0 + m1);
  float w0 = m0 * inv, w1 = m1 * inv;

  int r0 = atomicAdd(&hist[i0], 1);
  int r1 = atomicAdd(&hist[i1], 1);
  __syncthreads();
  if (tid < NE && hist[tid] > 0) basex[tid] = atomicAdd(&cnt[tid], hist[tid]);
  __syncthreads();

  int p0 = basex[i0] + r0;
  tokslot[(size_t)i0 * T_TOK + p0] = (t << 1);
  wgt[(size_t)i0 * T_TOK + p0] = w0;
  int p1 = basex[i1] + r1;
  tokslot[(size_t)i1 * T_TOK + p1] = (t << 1) | 1;
  wgt[(size_t)i1 * T_TOK + p1] = w1;
}

__global__ void calc_off(const int* __restrict__ cnt, int* __restrict__ offPad) {
  if (threadIdx.x == 0) {
    int s = 0;
    for (int e = 0; e < NE; ++e) { offPad[e] = s; s += (cnt[e] + 127) & ~127; }
    offPad[NE] = s;
  }
}

// ---------------------------------------------------------------------------
// Transpose+convert: in [E][K][N] f32 -> out [E][N][K] bf16  (64x64 tiles)
// ---------------------------------------------------------------------------
__global__ __launch_bounds__(256) void transpose_cvt(
    const float* __restrict__ in, unsigned short* __restrict__ out, int K, int N)
{
  __shared__ float tl[64][65];
  int e = blockIdx.z, kt = blockIdx.y, nt = blockIdx.x;
  const float* ib = in + (size_t)e * K * N + (size_t)(kt * 64) * N + nt * 64;
  int t = threadIdx.x;
  int r = t >> 2, c0 = (t & 3) * 16;
  #pragma unroll
  for (int i = 0; i < 4; ++i) {
    float4 v = *(const float4*)(ib + (size_t)r * N + c0 + i * 4);
    tl[r][c0+i*4+0] = v.x; tl[r][c0+i*4+1] = v.y;
    tl[r][c0+i*4+2] = v.z; tl[r][c0+i*4+3] = v.w;
  }
  __syncthreads();
  unsigned short* ob = out + (size_t)e * N * K + (size_t)(nt * 64) * K + kt * 64;
  #pragma unroll
  for (int i = 0; i < 2; ++i) {
    int u = t + i * 256;
    int n = u >> 3, k0 = (u & 7) * 8;
    us8 o;
    #pragma unroll
    for (int j = 0; j < 8; ++j) o[j] = f2bf(tl[k0 + j][n]);
    *(us8*)(ob + (size_t)n * K + k0) = o;
  }
}

// ---------------------------------------------------------------------------
// Gather routed tokens -> compact padded bf16 xg [rows][DM]
// ---------------------------------------------------------------------------
__global__ __launch_bounds__(256) void gather_x(
    const float* __restrict__ x, const int* __restrict__ tokslot,
    const int* __restrict__ cnt, const int* __restrict__ offPad,
    unsigned short* __restrict__ xg)
{
  int e = blockIdx.y;
  int n = cnt[e];
  int npad = (n + 127) & ~127;
  int r0 = blockIdx.x * 128;
  if (r0 >= npad) return;
  int t = threadIdx.x;
  int r = r0 + (t >> 1);
  int half = t & 1;
  unsigned short* orow = xg + (size_t)(offPad[e] + r) * DM + half * 256;
  if (r >= n) {
    us8 z = {0,0,0,0,0,0,0,0};
    #pragma unroll
    for (int i = 0; i < 32; ++i) *(us8*)(orow + i * 8) = z;
    return;
  }
  int tok = tokslot[(size_t)e * T_TOK + r] >> 1;
  const float* irow = x + (size_t)tok * DM + half * 256;
  #pragma unroll
  for (int i = 0; i < 32; ++i) {
    float4 a = *(const float4*)(irow + i * 8);
    float4 b = *(const float4*)(irow + i * 8 + 4);
    us8 o;
    o[0]=f2bf(a.x); o[1]=f2bf(a.y); o[2]=f2bf(a.z); o[3]=f2bf(a.w);
    o[4]=f2bf(b.x); o[5]=f2bf(b.y); o[6]=f2bf(b.z); o[7]=f2bf(b.w);
    *(us8*)(orow + i * 8) = o;
  }
}

// ---------------------------------------------------------------------------
// GEMM1: hidden = relu(xg @ W1t^T + b1).  W slice = 32 ff-cols x 512 K (33 KB
// LDS) -> 4 blocks/CU, 32 waves/CU (2x occupancy vs 64-col slice). Per wave:
// 32 rows x 32 cols, acc[2][2] (~45 VGPR, fits the (512,4) 64-cap; no spill).
// Grid 1024 = 16 experts x 64 chunks, XCD-swizzled.
// ---------------------------------------------------------------------------
__global__ __launch_bounds__(512, 4) void expert_gemm1(
    const unsigned short* __restrict__ xg, const unsigned short* __restrict__ W1t,
    const float* __restrict__ b1,
    const int* __restrict__ cnt, const int* __restrict__ offPad,
    unsigned short* __restrict__ hidden)
{
  __shared__ unsigned short wlds[32 * WROW];   // 33.3 KB
  int bid = blockIdx.x;
  int xcd = bid & 7, j = bid >> 3;             // j 0..127
  int e  = xcd * 2 + (j >> 6);
  int nb = (j & 63) * 32;
  int t = threadIdx.x, lane = t & 63, wv = t >> 6;
  int l15 = lane & 15, lg = lane >> 4;
  int wm = wv * 32;

  const unsigned short* w1b = W1t + ((size_t)e * DFF + nb) * DM;
  #pragma unroll
  for (int i = 0; i < 4; ++i) {
    int s = t + i * 512;                 // 0..2047 16B slots
    int r = s >> 6, c = s & 63;
    GLOAD_LDS16(w1b + (size_t)r * DM + c * 8, &wlds[r * WROW + c * 8]);
  }
  __syncthreads();

  int npad = (cnt[e] + 127) & ~127;
  int ebase = offPad[e];

  for (int tb = 0; tb < npad; tb += 256) {
    int r0 = wm, r1 = wm + 16;
    if (tb + r0 >= npad) r0 -= 128;
    if (tb + r1 >= npad) r1 -= 128;
    const unsigned short* a0p = xg + (size_t)(ebase + tb + r0 + l15) * DM;
    const unsigned short* a1p = xg + (size_t)(ebase + tb + r1 + l15) * DM;

    f32x4 acc[2][2];
    #pragma unroll
    for (int i = 0; i < 2; ++i)
      #pragma unroll
      for (int jj = 0; jj < 2; ++jj) acc[i][jj] = (f32x4){0.f, 0.f, 0.f, 0.f};

    #pragma unroll 2
    for (int kt = 0; kt < 8; ++kt) {
      #pragma unroll
      for (int kk = 0; kk < 2; ++kk) {
        int cidx = kt * 8 + kk * 4 + lg;         // 16B chunk in [0,64)
        bfrag a0 = *(const bfrag*)(a0p + (cidx << 3));
        bfrag a1 = *(const bfrag*)(a1p + (cidx << 3));
        bfrag b0 = *(const bfrag*)&wlds[(0 * 16 + l15) * WROW + cidx * 8];
        bfrag b1f = *(const bfrag*)&wlds[(1 * 16 + l15) * WROW + cidx * 8];
        acc[0][0] = __builtin_amdgcn_mfma_f32_16x16x32_bf16(a0, b0,  acc[0][0], 0, 0, 0);
        acc[0][1] = __builtin_amdgcn_mfma_f32_16x16x32_bf16(a0, b1f, acc[0][1], 0, 0, 0);
        acc[1][0] = __builtin_amdgcn_mfma_f32_16x16x32_bf16(a1, b0,  acc[1][0], 0, 0, 0);
        acc[1][1] = __builtin_amdgcn_mfma_f32_16x16x32_bf16(a1, b1f, acc[1][1], 0, 0, 0);
      }
    }

    int roff0 = r0, roff1 = r1;
    #pragma unroll
    for (int fj = 0; fj < 2; ++fj) {
      int col = nb + fj * 16 + l15;
      float bias = b1[(size_t)e * DFF + col];
      #pragma unroll
      for (int rg = 0; rg < 4; ++rg) {
        int rowA = ebase + tb + roff0 + lg * 4 + rg;
        float vA = acc[0][fj][rg] + bias;
        hidden[(size_t)rowA * DFF + col] = f2bf(vA > 0.f ? vA : 0.f);
        int rowB = ebase + tb + roff1 + lg * 4 + rg;
        float vB = acc[1][fj][rg] + bias;
        hidden[(size_t)rowB * DFF + col] = f2bf(vB > 0.f ? vB : 0.f);
      }
    }
  }
}

// ---------------------------------------------------------------------------
// GEMM2: y = hidden @ W2t^T (+ b2 on kq==0), split-K x4, scatter to 8 planes.
// Same 32-col W-resident structure: grid 1024 = 16 x (16 dm-chunks x 4 kq).
// ---------------------------------------------------------------------------
__global__ __launch_bounds__(512, 4) void expert_gemm2(
    const unsigned short* __restrict__ hidden, const unsigned short* __restrict__ W2t,
    const float* __restrict__ b2,
    const int* __restrict__ cnt, const int* __restrict__ offPad,
    const int* __restrict__ tokslot, const float* __restrict__ wgt,
    unsigned short* __restrict__ planes)
{
  __shared__ unsigned short wlds[32 * WROW];   // 33.3 KB
  int bid = blockIdx.x;
  int xcd = bid & 7, j = bid >> 3;             // j 0..127
  int e   = xcd * 2 + (j >> 6);
  int r6  = j & 63;
  int ncb = (r6 & 15) * 32;                    // dm chunk base
  int kq  = r6 >> 4;                           // K quarter
  int kb  = kq * 512;
  int t = threadIdx.x, lane = t & 63, wv = t >> 6;
  int l15 = lane & 15, lg = lane >> 4;
  int wm = wv * 32;

  const unsigned short* w2b = W2t + ((size_t)e * DM + ncb) * DFF + kb;
  #pragma unroll
  for (int i = 0; i < 4; ++i) {
    int s = t + i * 512;
    int r = s >> 6, c = s & 63;
    GLOAD_LDS16(w2b + (size_t)r * DFF + c * 8, &wlds[r * WROW + c * 8]);
  }
  __syncthreads();

  int n = cnt[e];
  int npad = (n + 127) & ~127;
  int ebase = offPad[e];

  for (int tb = 0; tb < npad; tb += 256) {
    int r0 = wm, r1 = wm + 16;
    if (tb + r0 >= npad) r0 -= 128;
    if (tb + r1 >= npad) r1 -= 128;
    const unsigned short* a0p = hidden + (size_t)(ebase + tb + r0 + l15) * DFF + kb;
    const unsigned short* a1p = hidden + (size_t)(ebase + tb + r1 + l15) * DFF + kb;

    f32x4 acc[2][2];
    #pragma unroll
    for (int i = 0; i < 2; ++i)
      #pragma unroll
      for (int jj = 0; jj < 2; ++jj) acc[i][jj] = (f32x4){0.f, 0.f, 0.f, 0.f};

    #pragma unroll 2
    for (int kt = 0; kt < 8; ++kt) {
      #pragma unroll
      for (int kk = 0; kk < 2; ++kk) {
        int cidx = kt * 8 + kk * 4 + lg;
        bfrag a0 = *(const bfrag*)(a0p + (cidx << 3));
        bfrag a1 = *(const bfrag*)(a1p + (cidx << 3));
        bfrag b0 = *(const bfrag*)&wlds[(0 * 16 + l15) * WROW + cidx * 8];
        bfrag b1f = *(const bfrag*)&wlds[(1 * 16 + l15) * WROW + cidx * 8];
        acc[0][0] = __builtin_amdgcn_mfma_f32_16x16x32_bf16(a0, b0,  acc[0][0], 0, 0, 0);
        acc[0][1] = __builtin_amdgcn_mfma_f32_16x16x32_bf16(a0, b1f, acc[0][1], 0, 0, 0);
        acc[1][0] = __builtin_amdgcn_mfma_f32_16x16x32_bf16(a1, b0,  acc[1][0], 0, 0, 0);
        acc[1][1] = __builtin_amdgcn_mfma_f32_16x16x32_bf16(a1, b1f, acc[1][1], 0, 0, 0);
      }
    }

    int roff[2] = {r0, r1};
    #pragma unroll
    for (int fi = 0; fi < 2; ++fi) {
      #pragma unroll
      for (int rg = 0; rg < 4; ++rg) {
        int idx = tb + roff[fi] + lg * 4 + rg;
        if (idx >= n) continue;
        int ts = tokslot[(size_t)e * T_TOK + idx];
        float w = wgt[(size_t)e * T_TOK + idx];
        unsigned short* pl = planes + ((size_t)(kq * 2 + (ts & 1)) * T_TOK + (ts >> 1)) * DM;
        #pragma unroll
        for (int fj = 0; fj < 2; ++fj) {
          int col = ncb + fj * 16 + l15;
          float bv = (kq == 0) ? b2[(size_t)e * DM + col] : 0.f;
          pl[col] = f2bf((acc[fi][fj][rg] + bv) * w);
        }
      }
    }
  }
}

// ---------------------------------------------------------------------------
// Combine: out[t][d] = sum over 8 bf16 planes
// ---------------------------------------------------------------------------
__global__ __launch_bounds__(256) void combine_out(
    const unsigned short* __restrict__ planes, float* __restrict__ out)
{
  int i = blockIdx.x * blockDim.x + threadIdx.x;
  float s[8] = {0.f};
  #pragma unroll
  for (int pl = 0; pl < 8; ++pl) {
    us8 v = *(const us8*)&planes[(size_t)pl * T_TOK * DM + (size_t)i * 8];
    #pragma unroll
    for (int jj = 0; jj < 8; ++jj) s[jj] += bf2f(v[jj]);
  }
  float4* o = (float4*)(out + (size_t)i * 8);
  o[0] = make_float4(s[0], s[1], s[2], s[3]);
  o[1] = make_float4(s[4], s[5], s[6], s[7]);
}

// ---------------------------------------------------------------------------
extern "C" void kernel_launch(void* const* d_in, const int* in_sizes, int n_in,
                              void* d_out, int out_size, void* d_ws, size_t ws_size,
                              hipStream_t stream)
{
  const float* x      = (const float*)d_in[0];
  const float* h_prev = (const float*)d_in[1];
  const float* Wp     = (const float*)d_in[2];
  const float* bp     = (const float*)d_in[3];
  const float* W_ih   = (const float*)d_in[4];
  const float* W_hh   = (const float*)d_in[5];
  const float* b_ih   = (const float*)d_in[6];
  const float* b_hh   = (const float*)d_in[7];
  const float* Wr     = (const float*)d_in[8];
  const float* br     = (const float*)d_in[9];
  const float* W1     = (const float*)d_in[10];
  const float* b1     = (const float*)d_in[11];
  const float* W2     = (const float*)d_in[12];
  const float* b2     = (const float*)d_in[13];
  (void)in_sizes; (void)n_in; (void)out_size; (void)ws_size;

  float* out  = (float*)d_out;                        // [T, DM]
  float* hout = out + (size_t)T_TOK * DM;             // [T, PP]

  char* ws = (char*)d_ws;
  // [0, 32M): W1t bf16 (read by gemm1) -> reused as 8 bf16 planes (gemm2)
  unsigned short* W1t    = (unsigned short*)(ws + 0);
  unsigned short* planes = (unsigned short*)(ws + 0);          // 8 x 4 MB
  // [32M, 64M): W2t bf16
  unsigned short* W2t = (unsigned short*)(ws + 33554432);
  // [64M, ~104M): hidden bf16 [10240][DFF]; routing temporaries overlap (dead first)
  unsigned short* hidden = (unsigned short*)(ws + 67108864);   // 40 MB
  float* gs     = (float*)(ws + 69206016);            // [T,512]  8 MB
  float* Bigcat = (float*)(ws + 77594624);            // [512][640] 1.31 MB
  float* bcat   = (float*)(ws + 78905344);            // [512]
  // [104M, ~114M): xg bf16 [10240][DM]
  unsigned short* xg = (unsigned short*)(ws + 109051904);
  // [~114M+): router lists
  float* wgt   = (float*)(ws + 119537664);            // [E,T]
  int* tokslot = (int*)(ws + 119799808);              // [E,T]
  int* cnt     = (int*)(ws + 120061952);              // [E]
  int* offPad  = (int*)(ws + 120062016);              // [E+1]

  // routing chain (f32; gates GEMM fused via Wx = W_ih@Wp)
  wx_gemm<<<dim3(8, 6), 256, 0, stream>>>(W_ih, Wp, Bigcat);
  fill_big<<<512, 256, 0, stream>>>(W_ih, W_hh, bp, b_ih, b_hh, Bigcat, bcat, cnt);
  sgemm_big<<<dim3(T_TOK/64, 512/64), 256, 0, stream>>>(x, h_prev, Bigcat, bcat, gs);
  gru_elem2<<<(T_TOK * PP) / 256, 256, 0, stream>>>(gs, h_prev, hout);
  router_topk2<<<64, 64, 0, stream>>>(hout, Wr, br, wgt, tokslot, cnt);
  calc_off<<<1, 64, 0, stream>>>(cnt, offPad);

  // weight transpose+convert
  transpose_cvt<<<dim3(DFF/64, DM/64, NE), 256, 0, stream>>>(W1, W1t, DM, DFF);
  transpose_cvt<<<dim3(DM/64, DFF/64, NE), 256, 0, stream>>>(W2, W2t, DFF, DM);

  // expert path: 32-col W-resident slices, 4 blocks/CU (2x occupancy)
  gather_x<<<dim3(32, NE), 256, 0, stream>>>(x, tokslot, cnt, offPad, xg);
  expert_gemm1<<<1024, 512, 0, stream>>>(xg, W1t, b1, cnt, offPad, hidden);
  expert_gemm2<<<1024, 512, 0, stream>>>(hidden, W2t, b2, cnt, offPad, tokslot, wgt, planes);
  combine_out<<<(T_TOK * DM / 8) / 256, 256, 0, stream>>>(planes, out);
}

// Round 14
// 242.706 us; speedup vs baseline: 1.4768x; 1.4768x over previous
//
#include <hip/hip_runtime.h>
#include <cmath>

#define T_TOK 4096
#define DM    512
#define DFF   2048
#define NE    16
#define PP    128
#define WROW  520   // padded LDS row stride in shorts (1040 B): 2-way conflicts = free

typedef __attribute__((ext_vector_type(8))) short bfrag;      // 8 bf16 (4 VGPRs)
typedef __attribute__((ext_vector_type(4))) float f32x4;
typedef __attribute__((ext_vector_type(8))) unsigned short us8;

__device__ __forceinline__ unsigned short f2bf(float f) {
  unsigned int u = __float_as_uint(f);
  unsigned int r = (u + 0x7FFFu + ((u >> 16) & 1u)) >> 16;
  return (unsigned short)r;
}
__device__ __forceinline__ float bf2f(unsigned short b) {
  return __uint_as_float(((unsigned int)b) << 16);
}

// ---------------------------------------------------------------------------
// f32 tiled SGEMM: C[M,N] = A[M,K] * B[N,K]^T + bias[N]   (routing chain)
// ---------------------------------------------------------------------------
__global__ __launch_bounds__(256) void sgemm_nt_bias(
    const float* __restrict__ A, const float* __restrict__ B,
    const float* __restrict__ bias, float* __restrict__ C,
    int M, int N, int K)
{
  __shared__ __align__(16) float As[16][68];
  __shared__ __align__(16) float Bs[16][68];
  const int bm = blockIdx.x * 64;
  const int bn = blockIdx.y * 64;
  const int tid = threadIdx.x;
  const int tx = tid & 15;
  const int ty = tid >> 4;

  float acc[4][4] = {{0.f}};

  for (int k0 = 0; k0 < K; k0 += 16) {
    {
      int r  = tid >> 2;
      int c4 = (tid & 3) * 4;
      float4 v = *(const float4*)(A + (size_t)(bm + r) * K + k0 + c4);
      As[c4+0][r] = v.x; As[c4+1][r] = v.y; As[c4+2][r] = v.z; As[c4+3][r] = v.w;
    }
    {
      int r  = tid >> 2;
      int c4 = (tid & 3) * 4;
      float4 v = *(const float4*)(B + (size_t)(bn + r) * K + k0 + c4);
      Bs[c4+0][r] = v.x; Bs[c4+1][r] = v.y; Bs[c4+2][r] = v.z; Bs[c4+3][r] = v.w;
    }
    __syncthreads();
    #pragma unroll
    for (int k = 0; k < 16; ++k) {
      float4 a4 = *(const float4*)&As[k][ty*4];
      float4 b4 = *(const float4*)&Bs[k][tx*4];
      float a[4] = {a4.x, a4.y, a4.z, a4.w};
      float b[4] = {b4.x, b4.y, b4.z, b4.w};
      #pragma unroll
      for (int i = 0; i < 4; ++i)
        #pragma unroll
        for (int j = 0; j < 4; ++j)
          acc[i][j] += a[i] * b[j];
    }
    __syncthreads();
  }
  #pragma unroll
  for (int i = 0; i < 4; ++i) {
    int row = bm + ty*4 + i;
    #pragma unroll
    for (int j = 0; j < 4; ++j) {
      int col = bn + tx*4 + j;
      C[(size_t)row * N + col] = acc[i][j] + bias[col];
    }
  }
}

// ---------------------------------------------------------------------------
// Fused gate GEMM: C[T,512] = [xp | h_prev] @ Bcat^T + bcat   (K = 256)
// ---------------------------------------------------------------------------
__global__ __launch_bounds__(256) void sgemm_cat(
    const float* __restrict__ A1, const float* __restrict__ A2,
    const float* __restrict__ B, const float* __restrict__ bias,
    float* __restrict__ C)
{
  __shared__ __align__(16) float As[16][68];
  __shared__ __align__(16) float Bs[16][68];
  const int bm = blockIdx.x * 64;
  const int bn = blockIdx.y * 64;
  const int tid = threadIdx.x;
  const int tx = tid & 15;
  const int ty = tid >> 4;

  float acc[4][4] = {{0.f}};

  for (int k0 = 0; k0 < 256; k0 += 16) {
    {
      int r  = tid >> 2;
      int c4 = (tid & 3) * 4;
      const float* src = (k0 < 128) ? (A1 + (size_t)(bm + r) * 128 + k0 + c4)
                                    : (A2 + (size_t)(bm + r) * 128 + (k0 - 128) + c4);
      float4 v = *(const float4*)src;
      As[c4+0][r] = v.x; As[c4+1][r] = v.y; As[c4+2][r] = v.z; As[c4+3][r] = v.w;
    }
    {
      int r  = tid >> 2;
      int c4 = (tid & 3) * 4;
      float4 v = *(const float4*)(B + (size_t)(bn + r) * 256 + k0 + c4);
      Bs[c4+0][r] = v.x; Bs[c4+1][r] = v.y; Bs[c4+2][r] = v.z; Bs[c4+3][r] = v.w;
    }
    __syncthreads();
    #pragma unroll
    for (int k = 0; k < 16; ++k) {
      float4 a4 = *(const float4*)&As[k][ty*4];
      float4 b4 = *(const float4*)&Bs[k][tx*4];
      float a[4] = {a4.x, a4.y, a4.z, a4.w};
      float b[4] = {b4.x, b4.y, b4.z, b4.w};
      #pragma unroll
      for (int i = 0; i < 4; ++i)
        #pragma unroll
        for (int j = 0; j < 4; ++j)
          acc[i][j] += a[i] * b[j];
    }
    __syncthreads();
  }
  #pragma unroll
  for (int i = 0; i < 4; ++i) {
    int row = bm + ty*4 + i;
    #pragma unroll
    for (int j = 0; j < 4; ++j) {
      int col = bn + tx*4 + j;
      C[(size_t)row * 512 + col] = acc[i][j] + bias[col];
    }
  }
}

// build Bcat [512][256] and bcat [512]; also zero cnt (block 0)
__global__ void prep_gates(const float* __restrict__ W_ih, const float* __restrict__ W_hh,
                           const float* __restrict__ b_ih, const float* __restrict__ b_hh,
                           float* __restrict__ Bcat, float* __restrict__ bcat,
                           int* __restrict__ cnt)
{
  int id = blockIdx.x * 256 + threadIdx.x;   // 131072
  if (blockIdx.x == 0 && threadIdx.x < NE) cnt[threadIdx.x] = 0;
  int n = id >> 8, k = id & 255;
  float v;
  if (n < 256)      v = (k < 128) ? W_ih[n * 128 + k] : W_hh[n * 128 + k - 128];
  else if (n < 384) v = (k < 128) ? W_ih[n * 128 + k] : 0.f;
  else              v = (k < 128) ? 0.f : W_hh[(n - 128) * 128 + k - 128];
  Bcat[n * 256 + k] = v;
  if (id < 512) {
    float b = (id < 256) ? (b_ih[id] + b_hh[id])
            : (id < 384) ? b_ih[id] : b_hh[id - 128];
    bcat[id] = b;
  }
}

// ---------------------------------------------------------------------------
// GRU elementwise from fused gate buffer s[T,512]
// ---------------------------------------------------------------------------
__global__ void gru_elem2(const float* __restrict__ s, const float* __restrict__ hprev,
                          float* __restrict__ hout)
{
  int i = blockIdx.x * blockDim.x + threadIdx.x;
  int t = i >> 7, p = i & 127;
  const float* sr = s + (size_t)t * 512;
  float rz = sr[p], zz = sr[128 + p], xn = sr[256 + p], hn = sr[384 + p];
  float r = 1.f / (1.f + expf(-rz));
  float z = 1.f / (1.f + expf(-zz));
  float n = tanhf(xn + r * hn);
  hout[i] = (1.f - z) * n + z * hprev[i];
}

// ---------------------------------------------------------------------------
// Router v2: one token per thread, Wr in LDS, per-block histogram ranking.
// ---------------------------------------------------------------------------
__global__ __launch_bounds__(64) void router_topk2(
    const float* __restrict__ h, const float* __restrict__ Wr,
    const float* __restrict__ br,
    float* __restrict__ wgt, int* __restrict__ tokslot,
    int* __restrict__ cnt)
{
  __shared__ float4 wr4[NE * 32];     // 8 KB
  __shared__ float br_s[NE];
  __shared__ int hist[NE];
  __shared__ int basex[NE];

  int tid = threadIdx.x;
  #pragma unroll
  for (int i = 0; i < 8; ++i)
    wr4[tid + i * 64] = ((const float4*)Wr)[tid + i * 64];
  if (tid < NE) { br_s[tid] = br[tid]; hist[tid] = 0; }
  __syncthreads();

  int t = blockIdx.x * 64 + tid;
  const float4* hr = (const float4*)(h + (size_t)t * PP);

  float logit[NE];
  #pragma unroll
  for (int e = 0; e < NE; ++e) logit[e] = 0.f;
  #pragma unroll 4
  for (int i = 0; i < 32; ++i) {
    float4 v = hr[i];
    #pragma unroll
    for (int e = 0; e < NE; ++e) {
      float4 w = wr4[e * 32 + i];
      logit[e] += v.x * w.x + v.y * w.y + v.z * w.z + v.w * w.w;
    }
  }
  #pragma unroll
  for (int e = 0; e < NE; ++e) logit[e] += br_s[e];

  float mx = logit[0];
  #pragma unroll
  for (int e = 1; e < NE; ++e) mx = fmaxf(mx, logit[e]);
  float p[NE];
  #pragma unroll
  for (int e = 0; e < NE; ++e) p[e] = expf(logit[e] - mx);
  int i0 = 0; float m0 = p[0];
  #pragma unroll
  for (int e = 1; e < NE; ++e) { if (p[e] > m0) { m0 = p[e]; i0 = e; } }
  int i1 = -1; float m1 = -1.f;
  #pragma unroll
  for (int e = 0; e < NE; ++e) { if (e != i0 && p[e] > m1) { m1 = p[e]; i1 = e; } }
  float inv = 1.f / (m0 + m1);
  float w0 = m0 * inv, w1 = m1 * inv;

  int r0 = atomicAdd(&hist[i0], 1);
  int r1 = atomicAdd(&hist[i1], 1);
  __syncthreads();
  if (tid < NE && hist[tid] > 0) basex[tid] = atomicAdd(&cnt[tid], hist[tid]);
  __syncthreads();

  int p0 = basex[i0] + r0;
  tokslot[(size_t)i0 * T_TOK + p0] = (t << 1);
  wgt[(size_t)i0 * T_TOK + p0] = w0;
  int p1 = basex[i1] + r1;
  tokslot[(size_t)i1 * T_TOK + p1] = (t << 1) | 1;
  wgt[(size_t)i1 * T_TOK + p1] = w1;
}

__global__ void calc_off(const int* __restrict__ cnt, int* __restrict__ offPad) {
  if (threadIdx.x == 0) {
    int s = 0;
    for (int e = 0; e < NE; ++e) { offPad[e] = s; s += (cnt[e] + 127) & ~127; }
    offPad[NE] = s;
  }
}

// ---------------------------------------------------------------------------
// Gather routed tokens -> compact padded bf16 xg [rows][DM]
// ---------------------------------------------------------------------------
__global__ __launch_bounds__(256) void gather_x(
    const float* __restrict__ x, const int* __restrict__ tokslot,
    const int* __restrict__ cnt, const int* __restrict__ offPad,
    unsigned short* __restrict__ xg)
{
  int e = blockIdx.y;
  int n = cnt[e];
  int npad = (n + 127) & ~127;
  int r0 = blockIdx.x * 128;
  if (r0 >= npad) return;
  int t = threadIdx.x;
  int r = r0 + (t >> 1);
  int half = t & 1;
  unsigned short* orow = xg + (size_t)(offPad[e] + r) * DM + half * 256;
  if (r >= n) {
    us8 z = {0,0,0,0,0,0,0,0};
    #pragma unroll
    for (int i = 0; i < 32; ++i) *(us8*)(orow + i * 8) = z;
    return;
  }
  int tok = tokslot[(size_t)e * T_TOK + r] >> 1;
  const float* irow = x + (size_t)tok * DM + half * 256;
  #pragma unroll
  for (int i = 0; i < 32; ++i) {
    float4 a = *(const float4*)(irow + i * 8);
    float4 b = *(const float4*)(irow + i * 8 + 4);
    us8 o;
    o[0]=f2bf(a.x); o[1]=f2bf(a.y); o[2]=f2bf(a.z); o[3]=f2bf(a.w);
    o[4]=f2bf(b.x); o[5]=f2bf(b.y); o[6]=f2bf(b.z); o[7]=f2bf(b.w);
    *(us8*)(orow + i * 8) = o;
  }
}

// ---------------------------------------------------------------------------
// GEMM1: hidden = relu(xg @ W1^T + b1).  W slice (64 ff cols x 512 dm) staged
// DIRECTLY from original f32 W1 [dm][ff] via transpose-through-LDS (coalesced
// float4 reads of 64 consecutive ff cols, f2bf, scattered ds_write). Removes
// the separate transpose_cvt pass entirely. Inner loop = r12 proven version.
// ---------------------------------------------------------------------------
__global__ __launch_bounds__(512, 2) void expert_gemm1(
    const unsigned short* __restrict__ xg, const float* __restrict__ W1,
    const float* __restrict__ b1,
    const int* __restrict__ cnt, const int* __restrict__ offPad,
    unsigned short* __restrict__ hidden)
{
  __shared__ unsigned short wlds[64 * WROW];   // 65 KB: [ff_local 64][dm 512] padded
  int bid = blockIdx.x;
  int xcd = bid & 7, j = bid >> 3;
  int e  = xcd * 2 + (j >> 5);
  int nb = (j & 31) * 64;
  int t = threadIdx.x, lane = t & 63, wv = t >> 6;
  int l15 = lane & 15, lg = lane >> 4;
  int wm = wv * 32;

  // stage: W1[e][r][nb + c] -> wlds[c][r]
  {
    const float* w1src = W1 + (size_t)e * DM * DFF + nb;
    int c4 = (t & 15) * 4, rr = t >> 4;
    #pragma unroll
    for (int pass = 0; pass < 16; ++pass) {
      int r = rr + pass * 32;
      float4 v = *(const float4*)(w1src + (size_t)r * DFF + c4);
      wlds[(c4+0) * WROW + r] = f2bf(v.x);
      wlds[(c4+1) * WROW + r] = f2bf(v.y);
      wlds[(c4+2) * WROW + r] = f2bf(v.z);
      wlds[(c4+3) * WROW + r] = f2bf(v.w);
    }
  }
  __syncthreads();

  int npad = (cnt[e] + 127) & ~127;
  int ebase = offPad[e];

  for (int tb = 0; tb < npad; tb += 256) {
    int r0 = wm, r1 = wm + 16;
    if (tb + r0 >= npad) r0 -= 128;
    if (tb + r1 >= npad) r1 -= 128;
    const unsigned short* a0p = xg + (size_t)(ebase + tb + r0 + l15) * DM;
    const unsigned short* a1p = xg + (size_t)(ebase + tb + r1 + l15) * DM;

    f32x4 acc[2][4];
    #pragma unroll
    for (int i = 0; i < 2; ++i)
      #pragma unroll
      for (int jj = 0; jj < 4; ++jj) acc[i][jj] = (f32x4){0.f, 0.f, 0.f, 0.f};

    #pragma unroll 2
    for (int kt = 0; kt < 8; ++kt) {
      #pragma unroll
      for (int kk = 0; kk < 2; ++kk) {
        int cidx = kt * 8 + kk * 4 + lg;         // 16B chunk index in [0,64)
        bfrag a0 = *(const bfrag*)(a0p + (cidx << 3));
        bfrag a1 = *(const bfrag*)(a1p + (cidx << 3));
        bfrag b0 = *(const bfrag*)&wlds[(0 * 16 + l15) * WROW + cidx * 8];
        bfrag b1f = *(const bfrag*)&wlds[(1 * 16 + l15) * WROW + cidx * 8];
        bfrag b2 = *(const bfrag*)&wlds[(2 * 16 + l15) * WROW + cidx * 8];
        bfrag b3 = *(const bfrag*)&wlds[(3 * 16 + l15) * WROW + cidx * 8];
        acc[0][0] = __builtin_amdgcn_mfma_f32_16x16x32_bf16(a0, b0,  acc[0][0], 0, 0, 0);
        acc[0][1] = __builtin_amdgcn_mfma_f32_16x16x32_bf16(a0, b1f, acc[0][1], 0, 0, 0);
        acc[0][2] = __builtin_amdgcn_mfma_f32_16x16x32_bf16(a0, b2,  acc[0][2], 0, 0, 0);
        acc[0][3] = __builtin_amdgcn_mfma_f32_16x16x32_bf16(a0, b3,  acc[0][3], 0, 0, 0);
        acc[1][0] = __builtin_amdgcn_mfma_f32_16x16x32_bf16(a1, b0,  acc[1][0], 0, 0, 0);
        acc[1][1] = __builtin_amdgcn_mfma_f32_16x16x32_bf16(a1, b1f, acc[1][1], 0, 0, 0);
        acc[1][2] = __builtin_amdgcn_mfma_f32_16x16x32_bf16(a1, b2,  acc[1][2], 0, 0, 0);
        acc[1][3] = __builtin_amdgcn_mfma_f32_16x16x32_bf16(a1, b3,  acc[1][3], 0, 0, 0);
      }
    }

    int roff0 = r0, roff1 = r1;
    #pragma unroll
    for (int fj = 0; fj < 4; ++fj) {
      int col = nb + fj * 16 + l15;
      float bias = b1[(size_t)e * DFF + col];
      #pragma unroll
      for (int rg = 0; rg < 4; ++rg) {
        int rowA = ebase + tb + roff0 + lg * 4 + rg;
        float vA = acc[0][fj][rg] + bias;
        hidden[(size_t)rowA * DFF + col] = f2bf(vA > 0.f ? vA : 0.f);
        int rowB = ebase + tb + roff1 + lg * 4 + rg;
        float vB = acc[1][fj][rg] + bias;
        hidden[(size_t)rowB * DFF + col] = f2bf(vB > 0.f ? vB : 0.f);
      }
    }
  }
}

// ---------------------------------------------------------------------------
// GEMM2: y = hidden @ W2^T (+ b2 on kq==0), split-K x4, scatter to 8 planes.
// W slice (64 dm cols x 512 ff) staged directly from f32 W2 [ff][dm].
// Inner loop = r7/r12 proven version ((512,4), VGPR 60, no spill), with
// padded-LDS B reads instead of XOR swizzle.
// ---------------------------------------------------------------------------
__global__ __launch_bounds__(512, 4) void expert_gemm2(
    const unsigned short* __restrict__ hidden, const float* __restrict__ W2,
    const float* __restrict__ b2,
    const int* __restrict__ cnt, const int* __restrict__ offPad,
    const int* __restrict__ tokslot, const float* __restrict__ wgt,
    unsigned short* __restrict__ planes)
{
  __shared__ unsigned short wlds[64 * WROW];   // 65 KB: [dm_local 64][ff 512] padded
  int bid = blockIdx.x;
  int xcd = bid & 7, j = bid >> 3;
  int e   = xcd * 2 + (j >> 5);
  int r5  = j & 31;
  int ncb = (r5 & 7) * 64;                    // dm chunk base
  int kq  = r5 >> 3;                          // K quarter
  int kb  = kq * 512;
  int t = threadIdx.x, lane = t & 63, wv = t >> 6;
  int l15 = lane & 15, lg = lane >> 4;
  int wm = wv * 32;

  // stage: W2[e][kb + f][ncb + c] -> wlds[c][f]
  {
    const float* w2src = W2 + (size_t)e * DFF * DM + (size_t)kb * DM + ncb;
    int c4 = (t & 15) * 4, fr = t >> 4;
    #pragma unroll
    for (int pass = 0; pass < 16; ++pass) {
      int f = fr + pass * 32;
      float4 v = *(const float4*)(w2src + (size_t)f * DM + c4);
      wlds[(c4+0) * WROW + f] = f2bf(v.x);
      wlds[(c4+1) * WROW + f] = f2bf(v.y);
      wlds[(c4+2) * WROW + f] = f2bf(v.z);
      wlds[(c4+3) * WROW + f] = f2bf(v.w);
    }
  }
  __syncthreads();

  int n = cnt[e];
  int npad = (n + 127) & ~127;
  int ebase = offPad[e];

  for (int tb = 0; tb < npad; tb += 256) {
    int roff[2];
    #pragma unroll
    for (int fi = 0; fi < 2; ++fi) {
      int r0 = wm + fi * 16;
      roff[fi] = (tb + r0 >= npad) ? r0 - 128 : r0;
    }
    f32x4 acc[2][4];
    #pragma unroll
    for (int i = 0; i < 2; ++i)
      #pragma unroll
      for (int jj = 0; jj < 4; ++jj) acc[i][jj] = (f32x4){0.f, 0.f, 0.f, 0.f};

    #pragma unroll 2
    for (int kt = 0; kt < 8; ++kt) {
      #pragma unroll
      for (int kk = 0; kk < 2; ++kk) {
        int cidx = kt * 8 + kk * 4 + lg;
        bfrag a[2], b[4];
        #pragma unroll
        for (int fi = 0; fi < 2; ++fi)
          a[fi] = *(const bfrag*)(hidden + (size_t)(ebase + tb + roff[fi] + l15) * DFF + kb + (cidx << 3));
        #pragma unroll
        for (int fj = 0; fj < 4; ++fj) {
          int row = fj * 16 + l15;
          b[fj] = *(const bfrag*)&wlds[row * WROW + cidx * 8];
        }
        #pragma unroll
        for (int fi = 0; fi < 2; ++fi)
          #pragma unroll
          for (int fj = 0; fj < 4; ++fj)
            acc[fi][fj] = __builtin_amdgcn_mfma_f32_16x16x32_bf16(a[fi], b[fj], acc[fi][fj], 0, 0, 0);
      }
    }

    #pragma unroll
    for (int fi = 0; fi < 2; ++fi) {
      #pragma unroll
      for (int rg = 0; rg < 4; ++rg) {
        int idx = tb + roff[fi] + lg * 4 + rg;
        if (idx >= n) continue;
        int ts = tokslot[(size_t)e * T_TOK + idx];
        float w = wgt[(size_t)e * T_TOK + idx];
        unsigned short* pl = planes + ((size_t)(kq * 2 + (ts & 1)) * T_TOK + (ts >> 1)) * DM;
        #pragma unroll
        for (int fj = 0; fj < 4; ++fj) {
          int col = ncb + fj * 16 + l15;
          float bv = (kq == 0) ? b2[(size_t)e * DM + col] : 0.f;
          pl[col] = f2bf((acc[fi][fj][rg] + bv) * w);
        }
      }
    }
  }
}

// ---------------------------------------------------------------------------
// Combine: out[t][d] = sum over 8 bf16 planes
// ---------------------------------------------------------------------------
__global__ __launch_bounds__(256) void combine_out(
    const unsigned short* __restrict__ planes, float* __restrict__ out)
{
  int i = blockIdx.x * blockDim.x + threadIdx.x;
  float s[8] = {0.f};
  #pragma unroll
  for (int pl = 0; pl < 8; ++pl) {
    us8 v = *(const us8*)&planes[(size_t)pl * T_TOK * DM + (size_t)i * 8];
    #pragma unroll
    for (int jj = 0; jj < 8; ++jj) s[jj] += bf2f(v[jj]);
  }
  float4* o = (float4*)(out + (size_t)i * 8);
  o[0] = make_float4(s[0], s[1], s[2], s[3]);
  o[1] = make_float4(s[4], s[5], s[6], s[7]);
}

// ---------------------------------------------------------------------------
extern "C" void kernel_launch(void* const* d_in, const int* in_sizes, int n_in,
                              void* d_out, int out_size, void* d_ws, size_t ws_size,
                              hipStream_t stream)
{
  const float* x      = (const float*)d_in[0];
  const float* h_prev = (const float*)d_in[1];
  const float* Wp     = (const float*)d_in[2];
  const float* bp     = (const float*)d_in[3];
  const float* W_ih   = (const float*)d_in[4];
  const float* W_hh   = (const float*)d_in[5];
  const float* b_ih   = (const float*)d_in[6];
  const float* b_hh   = (const float*)d_in[7];
  const float* Wr     = (const float*)d_in[8];
  const float* br     = (const float*)d_in[9];
  const float* W1     = (const float*)d_in[10];
  const float* b1     = (const float*)d_in[11];
  const float* W2     = (const float*)d_in[12];
  const float* b2     = (const float*)d_in[13];
  (void)in_sizes; (void)n_in; (void)out_size; (void)ws_size;

  float* out  = (float*)d_out;                        // [T, DM]
  float* hout = out + (size_t)T_TOK * DM;             // [T, PP]

  char* ws = (char*)d_ws;
  unsigned short* planes = (unsigned short*)(ws + 0);          // 8 planes bf16, 33.6 MB
  unsigned short* hidden = (unsigned short*)(ws + 35651584);   // [10240][DFF] bf16, 40 MB
  unsigned short* xg     = (unsigned short*)(ws + 79691776);   // [10240][DM] bf16, 10.5 MB
  float* xp   = (float*)(ws + 92274688);              // [T,128]   2 MB
  float* gs   = (float*)(ws + 94371840);              // [T,512]   8 MB
  float* Bcat = (float*)(ws + 102760448);             // [512][256] 512 KB
  float* bcat = (float*)(ws + 103284736);             // [512]
  float* wgt  = (float*)(ws + 103809024);             // [E,T]
  int* tokslot = (int*)(ws + 104071168);              // [E,T]
  int* cnt     = (int*)(ws + 104333312);              // [E]
  int* offPad  = (int*)(ws + 104333376);              // [E+1]

  // routing chain (f32 end-to-end for exact top-k); prep_gates also zeroes cnt
  prep_gates<<<512, 256, 0, stream>>>(W_ih, W_hh, b_ih, b_hh, Bcat, bcat, cnt);
  sgemm_nt_bias<<<dim3(T_TOK/64, PP/64), 256, 0, stream>>>(x, Wp, bp, xp, T_TOK, PP, DM);
  sgemm_cat<<<dim3(T_TOK/64, 512/64), 256, 0, stream>>>(xp, h_prev, Bcat, bcat, gs);
  gru_elem2<<<(T_TOK * PP) / 256, 256, 0, stream>>>(gs, h_prev, hout);
  router_topk2<<<64, 64, 0, stream>>>(hout, Wr, br, wgt, tokslot, cnt);
  calc_off<<<1, 64, 0, stream>>>(cnt, offPad);

  // expert path: W staged directly from original f32 layout (no transpose pass)
  gather_x<<<dim3(32, NE), 256, 0, stream>>>(x, tokslot, cnt, offPad, xg);
  expert_gemm1<<<512, 512, 0, stream>>>(xg, W1, b1, cnt, offPad, hidden);
  expert_gemm2<<<512, 512, 0, stream>>>(hidden, W2, b2, cnt, offPad, tokslot, wgt, planes);
  combine_out<<<(T_TOK * DM / 8) / 256, 256, 0, stream>>>(planes, out);
}